// Round 13
// baseline (164.941 us; speedup 1.0000x reference)
//
#include <hip/hip_runtime.h>
#include <hip/hip_bf16.h>

typedef short s16x8 __attribute__((ext_vector_type(8)));
typedef float f32x4 __attribute__((ext_vector_type(4)));
typedef unsigned u32x4 __attribute__((ext_vector_type(4)));
typedef unsigned short u16;

#define LOG2E 1.4426950408889634f
#define QSC (0.125f * LOG2E)   // softmax scale (Dh=64 -> 1/8) * log2(e), folded into alpha_q/bias_q

typedef __attribute__((address_space(3))) unsigned int lds_u32;
typedef __attribute__((address_space(1))) const unsigned int glb_u32;

static __device__ __forceinline__ void gload16(const void* g, void* l) {
  __builtin_amdgcn_global_load_lds((glb_u32*)g, (lds_u32*)l, 16, 0, 0);
}
static __device__ __forceinline__ u16 bf16u(float f) {
  unsigned u = __builtin_bit_cast(unsigned, f);
  return (u16)((u + 0x7FFFu + ((u >> 16) & 1u)) >> 16);  // RNE
}
static __device__ __forceinline__ unsigned pk(u16 a, u16 b) {
  return (unsigned)a | ((unsigned)b << 16);
}
// packed RNE f32x2 -> bf16x2, single HW op (no builtin on gfx950 - T12 recipe)
static __device__ __forceinline__ unsigned cvtpk(float lo, float hi) {
  unsigned d;
  asm("v_cvt_pk_bf16_f32 %0, %1, %2" : "=v"(d) : "v"(lo), "v"(hi));
  return d;
}
// header path (used only in non-hot prep)
static __device__ __forceinline__ unsigned pk2(float a, float b) {
  float2 f; f.x = a; f.y = b;
  __hip_bfloat162 h = __float22bfloat162_rn(f);
  unsigned r;
  __builtin_memcpy(&r, &h, 4);
  return r;
}

// ---------------------------------------------------------------------------
// Prep (merged): blocks 0..1023 binarize weights; blocks 1024..5119 cvt x.
// ---------------------------------------------------------------------------
__global__ __launch_bounds__(256) void k_prep(
    const float* __restrict__ x, u16* __restrict__ xb,
    const float* __restrict__ Wq, const float* __restrict__ Wk,
    const float* __restrict__ Wv, const float* __restrict__ Wp,
    const float* __restrict__ bq, const float* __restrict__ bk,
    const float* __restrict__ bv, const float* __restrict__ bp,
    u16* __restrict__ wbqkv, u16* __restrict__ wbp,
    float* __restrict__ alphaf, float* __restrict__ biasf) {
  if (blockIdx.x >= 1024) {
    int i = ((blockIdx.x - 1024) * 256 + threadIdx.x) * 8;
    float4 a = *reinterpret_cast<const float4*>(x + i);
    float4 b = *reinterpret_cast<const float4*>(x + i + 4);
    uint4 w = { pk2(a.x, a.y), pk2(a.z, a.w), pk2(b.x, b.y), pk2(b.z, b.w) };
    *reinterpret_cast<uint4*>(xb + i) = w;
    return;
  }
  int wave = threadIdx.x >> 6, lane = threadIdx.x & 63;
  int row = blockIdx.x * 4 + wave;
  const float* src; const float* bias; int r;
  if (row < 1024)      { src = Wq; bias = bq; r = row; }
  else if (row < 2048) { src = Wk; bias = bk; r = row - 1024; }
  else if (row < 3072) { src = Wv; bias = bv; r = row - 2048; }
  else                 { src = Wp; bias = bp; r = row - 3072; }
  const float4* s4 = reinterpret_cast<const float4*>(src + r * 1024);
  float4 v[4];
  float asum = 0.f;
#pragma unroll
  for (int i = 0; i < 4; ++i) {
    v[i] = s4[lane * 4 + i];
    asum += fabsf(v[i].x) + fabsf(v[i].y) + fabsf(v[i].z) + fabsf(v[i].w);
  }
#pragma unroll
  for (int m = 32; m >= 1; m >>= 1) asum += __shfl_xor(asum, m, 64);
  float alpha = asum * (1.0f / 1024.0f);

  u16 o[16];
#pragma unroll
  for (int i = 0; i < 4; ++i) {
    const float* f = reinterpret_cast<const float*>(&v[i]);
#pragma unroll
    for (int j = 0; j < 4; ++j) {
      float w = f[j];
      o[i * 4 + j] = (w > 0.f) ? (u16)0x3F80 : ((w < 0.f) ? (u16)0xBF80 : (u16)0);
    }
  }
  u16* dst = (row < 3072 ? wbqkv + row * 1024 : wbp + (row - 3072) * 1024) + lane * 16;
  uint4 w0 = { pk(o[0],o[1]), pk(o[2],o[3]), pk(o[4],o[5]), pk(o[6],o[7]) };
  uint4 w1 = { pk(o[8],o[9]), pk(o[10],o[11]), pk(o[12],o[13]), pk(o[14],o[15]) };
  reinterpret_cast<uint4*>(dst)[0] = w0;
  reinterpret_cast<uint4*>(dst)[1] = w1;
  if (lane == 0) {
    float sc = (row < 1024) ? QSC : 1.0f;
    alphaf[row] = alpha * sc;
    biasf[row]  = bias[r] * sc;
  }
}

// ---------------------------------------------------------------------------
// GEMM v2 (unchanged from R11, passing): 128x128 tile, BK=64, 4 waves,
// 16x16x32 MFMA, XCD-swizzled grid, double-buffered staging.
// ---------------------------------------------------------------------------
template <int MODE, int NX, int NWG>
__global__ __launch_bounds__(256) void k_gemm(
    const u16* __restrict__ A, const u16* __restrict__ Bw,
    const float* __restrict__ alphaf, const float* __restrict__ biasf,
    u16* __restrict__ qbuf, u16* __restrict__ kbuf, u16* __restrict__ vtbuf,
    float* __restrict__ outf) {
  __shared__ alignas(128) char smem[65536];  // 2 x (A 16K | B 16K)
  int tid = threadIdx.x;
  int wave = tid >> 6, l = tid & 63, g = l >> 4, ln = l & 15;
  int wm = (wave >> 1) * 64, wn = (wave & 1) * 64;
  int wg = (blockIdx.x & 7) * (NWG / 8) + (blockIdx.x >> 3);  // XCD swizzle
  int m0 = (wg / NX) * 128, n0 = (wg % NX) * 128;

  f32x4 acc[4][4];
#pragma unroll
  for (int i = 0; i < 4; ++i)
#pragma unroll
    for (int j = 0; j < 4; ++j) acc[i][j] = f32x4{0.f, 0.f, 0.f, 0.f};

  const char* Ab = reinterpret_cast<const char*>(A) + m0 * 2048;
  const char* Bb = reinterpret_cast<const char*>(Bw) + n0 * 2048;

  int soff[4];
#pragma unroll
  for (int i = 0; i < 4; ++i) {
    int P = i * 4096 + tid * 16;
    int r = P >> 7;
    int kc = ((P >> 4) & 7) ^ (r & 7);
    soff[i] = r * 2048 + kc * 16;
  }

  // prologue: stage K-step 0 into buf0
#pragma unroll
  for (int i = 0; i < 4; ++i)
    gload16(Ab + soff[i], smem + i * 4096 + wave * 1024);
#pragma unroll
  for (int i = 0; i < 4; ++i)
    gload16(Bb + soff[i], smem + 16384 + i * 4096 + wave * 1024);
  __syncthreads();

  for (int ks = 0; ks < 16; ++ks) {
    int cb = ks & 1;
    if (ks < 15) {  // prefetch next K-step into the other buffer
      char* nb = smem + (cb ^ 1) * 32768;
      int kb0 = (ks + 1) * 128;
#pragma unroll
      for (int i = 0; i < 4; ++i)
        gload16(Ab + soff[i] + kb0, nb + i * 4096 + wave * 1024);
#pragma unroll
      for (int i = 0; i < 4; ++i)
        gload16(Bb + soff[i] + kb0, nb + 16384 + i * 4096 + wave * 1024);
    }
    const char* As = smem + cb * 32768;
    const char* Bs = As + 16384;
#pragma unroll
    for (int kk = 0; kk < 2; ++kk) {
      s16x8 af[4], bfr[4];
#pragma unroll
      for (int mf = 0; mf < 4; ++mf) {
        int r = wm + mf * 16 + ln;
        int kb = (kk * 64 + g * 16) ^ ((r & 7) << 4);
        af[mf] = *reinterpret_cast<const s16x8*>(As + r * 128 + kb);
      }
#pragma unroll
      for (int nf = 0; nf < 4; ++nf) {
        int r = wn + nf * 16 + ln;
        int kb = (kk * 64 + g * 16) ^ ((r & 7) << 4);
        bfr[nf] = *reinterpret_cast<const s16x8*>(Bs + r * 128 + kb);
      }
#pragma unroll
      for (int mf = 0; mf < 4; ++mf)
#pragma unroll
        for (int nf = 0; nf < 4; ++nf)
          acc[mf][nf] = __builtin_amdgcn_mfma_f32_16x16x32_bf16(af[mf], bfr[nf], acc[mf][nf], 0, 0, 0);
    }
    __syncthreads();  // drains prefetch vmcnt; buf swap safe
  }

  if (MODE == 0) {
    if (n0 < 2048) {
      u16* dst = (n0 < 1024) ? qbuf : kbuf;
#pragma unroll
      for (int nf = 0; nf < 4; ++nf) {
        int n = n0 + wn + nf * 16 + ln;
        float al = alphaf[n], bi = biasf[n];
        int nl = n & 1023;
        int h = nl >> 6, d = nl & 63;
#pragma unroll
        for (int mf = 0; mf < 4; ++mf)
#pragma unroll
          for (int rg = 0; rg < 4; ++rg) {
            int m = m0 + wm + mf * 16 + g * 4 + rg;
            int b = m >> 11, t = m & 2047;
            dst[(((b * 16 + h) * 2048 + t) << 6) + d] = bf16u(al * acc[mf][nf][rg] + bi);
          }
      }
    } else {
      u16* ldsT = reinterpret_cast<u16*>(smem);
#pragma unroll
      for (int nf = 0; nf < 4; ++nf) {
        int n = n0 + wn + nf * 16 + ln;
        float al = alphaf[n], bi = biasf[n];
        int nloc = wn + nf * 16 + ln;
#pragma unroll
        for (int mf = 0; mf < 4; ++mf)
#pragma unroll
          for (int rg = 0; rg < 4; ++rg) {
            int mloc = wm + mf * 16 + g * 4 + rg;
            ldsT[mloc * 132 + nloc] = bf16u(al * acc[mf][nf][rg] + bi);
          }
      }
      __syncthreads();
      int dl = tid >> 1;
      int sh = (tid & 1) * 64;
      int nv = n0 - 2048 + dl;
      int h = nv >> 6, d = nv & 63;
      int b = m0 >> 11;
      int s0 = (m0 & 2047) + sh;
      u16* vdst = vtbuf + (((b * 16 + h) * 64 + d) << 11) + s0;
#pragma unroll
      for (int c8 = 0; c8 < 8; ++c8) {
        u16 t0 = ldsT[(sh + c8 * 8 + 0) * 132 + dl], t1 = ldsT[(sh + c8 * 8 + 1) * 132 + dl];
        u16 t2 = ldsT[(sh + c8 * 8 + 2) * 132 + dl], t3 = ldsT[(sh + c8 * 8 + 3) * 132 + dl];
        u16 t4 = ldsT[(sh + c8 * 8 + 4) * 132 + dl], t5 = ldsT[(sh + c8 * 8 + 5) * 132 + dl];
        u16 t6 = ldsT[(sh + c8 * 8 + 6) * 132 + dl], t7 = ldsT[(sh + c8 * 8 + 7) * 132 + dl];
        uint4 w = { pk(t0, t1), pk(t2, t3), pk(t4, t5), pk(t6, t7) };
        *reinterpret_cast<uint4*>(vdst + c8 * 8) = w;
      }
    }
  } else {
#pragma unroll
    for (int nf = 0; nf < 4; ++nf) {
      int n = n0 + wn + nf * 16 + ln;
      float al = alphaf[3072 + n], bi = biasf[3072 + n];
#pragma unroll
      for (int mf = 0; mf < 4; ++mf)
#pragma unroll
        for (int rg = 0; rg < 4; ++rg) {
          int m = m0 + wm + mf * 16 + g * 4 + rg;
          outf[m * 1024 + n] = al * acc[mf][nf][rg] + bi;
        }
    }
  }
}

// ---------------------------------------------------------------------------
// Flash attention v7: occupancy-doubled. 8 waves x 16 q-rows (1 q-set/wave),
// 128 q/block, grid 1024 -> 4 blocks/CU = 32 waves/CU = 8 waves/SIMD
// (R11 counters: MfmaUtil 47 + VALUBusy 44 ~ serialized pipes at 4 waves/
// SIMD; more wave slots let MFMA/VALU/DS phases of different waves overlap).
// Same math: K-row permutation -> lane-local P, fixed m=0, ones-MFMA l,
// zero-conflict swizzle, single-op cvt_pk packing. VGPR capped 64 via
// __launch_bounds__(512,8).
// ---------------------------------------------------------------------------
__global__ __launch_bounds__(512, 8) void k_attn(
    const u16* __restrict__ qb, const u16* __restrict__ kb,
    const u16* __restrict__ vtb, u16* __restrict__ yb) {
  __shared__ alignas(128) char smem[32768];  // [buf0: K 8K | V 8K][buf1: ...]
  int tid = threadIdx.x;
  int wave = tid >> 6, lane = tid & 63;
  int g = lane >> 4, ln = lane & 15;

  // XCD swizzle: 128 consecutive wg per XCD -> 8 bh per XCD (4MB K/V = L2)
  int wg = (blockIdx.x & 7) * 128 + (blockIdx.x >> 3);
  int bh = wg >> 4, qt = wg & 15;
  const char* Qg = reinterpret_cast<const char*>(qb) + bh * 262144;
  const char* Kg = reinterpret_cast<const char*>(kb) + bh * 262144;
  const char* Vg = reinterpret_cast<const char*>(vtb) + bh * 262144;  // [64 d][2048 s]

  // Q fragments: lane (g,ln) holds Q[qrow][k = 32kt + 8g + j]
  int qrow = qt * 128 + wave * 16 + ln;
  const s16x8* Qr = reinterpret_cast<const s16x8*>(Qg + qrow * 128);
  s16x8 qf0 = Qr[g], qf1 = Qr[g + 4];

  s16x8 ones;
#pragma unroll
  for (int i = 0; i < 8; ++i) ones[i] = (short)0x3F80;

  // staging offsets: source pre-swizzled with w(r) = (r&3)|(bit3(r)<<2)
  int r = tid >> 3, kc = tid & 7;
  int wr = (r & 3) | (((r >> 3) & 1) << 2);
  int swsrc = (kc ^ wr) * 16;
  int ksrc = r * 128 + swsrc;
  int vsrc = r * 4096 + swsrc;

  // read-side XOR bytes
  int swK = (ln & 7) << 4;                              // w(rho) = ln&7
  int swV = ((ln & 3) | (((ln >> 3) & 1) << 2)) << 4;   // w(dt*16+ln)

  f32x4 oacc[4];
#pragma unroll
  for (int i = 0; i < 4; ++i) oacc[i] = f32x4{0.f, 0.f, 0.f, 0.f};
  f32x4 lacc = f32x4{0.f, 0.f, 0.f, 0.f};

  // prologue: stage tile 0 into buf0
  gload16(Kg + ksrc, smem + wave * 1024);
  gload16(Vg + vsrc, smem + 8192 + wave * 1024);
  __syncthreads();

  for (int st = 0; st < 32; ++st) {
    int cb = st & 1;
    if (st < 31) {  // prefetch next tile into the other buffer
      int sb = (st + 1) * 64;
      char* nb = smem + (cb ^ 1) * 16384;
      gload16(Kg + sb * 128 + ksrc, nb + wave * 1024);
      gload16(Vg + sb * 2 + vsrc, nb + 8192 + wave * 1024);
    }
    const char* Kb = smem + cb * 16384;
    const char* Vb = Kb + 8192;

    // S^T = mfma(K,Q) with permuted K rows:
    // sacc[t] reg rg = S[q][s = 32(t&1) + 8g + 4(t>>1) + rg]
    f32x4 sacc[4];
#pragma unroll
    for (int t = 0; t < 4; ++t) sacc[t] = f32x4{0.f, 0.f, 0.f, 0.f};
    __builtin_amdgcn_s_setprio(1);
#pragma unroll
    for (int kt = 0; kt < 2; ++kt) {
      s16x8 qf = kt ? qf1 : qf0;
      int off = (kt * 64 + g * 16) ^ swK;
#pragma unroll
      for (int t = 0; t < 4; ++t) {
        int rho = 32 * (t & 1) + 8 * (ln >> 2) + 4 * (t >> 1) + (ln & 3);
        s16x8 kf = *reinterpret_cast<const s16x8*>(Kb + rho * 128 + off);
        sacc[t] = __builtin_amdgcn_mfma_f32_16x16x32_bf16(kf, qf, sacc[t], 0, 0, 0);
      }
    }
    __builtin_amdgcn_s_setprio(0);

    // P = exp2(S) (m fixed 0) -> lane-local PV B-fragments (no LDS)
    float p[4][4];
#pragma unroll
    for (int t = 0; t < 4; ++t)
#pragma unroll
      for (int rg = 0; rg < 4; ++rg)
        p[t][rg] = __builtin_amdgcn_exp2f(sacc[t][rg]);
    s16x8 pf[2];
#pragma unroll
    for (int kt = 0; kt < 2; ++kt) {
      u32x4 tw;
      tw[0] = cvtpk(p[kt][0],     p[kt][1]);
      tw[1] = cvtpk(p[kt][2],     p[kt][3]);
      tw[2] = cvtpk(p[kt + 2][0], p[kt + 2][1]);
      tw[3] = cvtpk(p[kt + 2][2], p[kt + 2][3]);
      pf[kt] = __builtin_bit_cast(s16x8, tw);
    }

    // l += ones . P  (A=ones: layout-independent row sums into lacc[rg])
#pragma unroll
    for (int kt = 0; kt < 2; ++kt)
      lacc = __builtin_amdgcn_mfma_f32_16x16x32_bf16(ones, pf[kt], lacc, 0, 0, 0);

    // O^T += mfma(V,P)
    __builtin_amdgcn_s_setprio(1);
#pragma unroll
    for (int kt = 0; kt < 2; ++kt) {
      int off = (kt * 64 + g * 16) ^ swV;
#pragma unroll
      for (int dt = 0; dt < 4; ++dt) {
        s16x8 vf = *reinterpret_cast<const s16x8*>(Vb + (dt * 16 + ln) * 128 + off);
        oacc[dt] = __builtin_amdgcn_mfma_f32_16x16x32_bf16(vf, pf[kt], oacc[dt], 0, 0, 0);
      }
    }
    __builtin_amdgcn_s_setprio(0);
    __syncthreads();  // drains vmcnt (prefetch) + lgkm; buf swap safe
  }

  // epilogue: y[b, t, h*64 + d] = O[d][q]/l, d = 16dt + 4g + rg
  float linv = 1.0f / lacc[0];
  int b = bh >> 4, h = bh & 15;
  u16* yrow = yb + (b * 2048 + qrow) * 1024 + h * 64;
#pragma unroll
  for (int dt = 0; dt < 4; ++dt) {
    uint2 w;
    w.x = cvtpk(oacc[dt][0] * linv, oacc[dt][1] * linv);
    w.y = cvtpk(oacc[dt][2] * linv, oacc[dt][3] * linv);
    *reinterpret_cast<uint2*>(yrow + dt * 16 + g * 4) = w;
  }
}

// ---------------------------------------------------------------------------
extern "C" void kernel_launch(void* const* d_in, const int* in_sizes, int n_in,
                              void* d_out, int out_size, void* d_ws, size_t ws_size,
                              hipStream_t stream) {
  (void)in_sizes; (void)n_in; (void)out_size; (void)ws_size;
  const float* x  = (const float*)d_in[0];
  const float* Wq = (const float*)d_in[1];
  const float* bq = (const float*)d_in[2];
  const float* Wk = (const float*)d_in[3];
  const float* bk = (const float*)d_in[4];
  const float* Wv = (const float*)d_in[5];
  const float* bv = (const float*)d_in[6];
  const float* Wp = (const float*)d_in[7];
  const float* bp = (const float*)d_in[8];

  char* ws = (char*)d_ws;
  u16*   xb    = (u16*)(ws);               // 16MB (reused as Y after attention)
  u16*   wbqkv = (u16*)(ws + 16777216);    // 6MB
  u16*   wbp   = (u16*)(ws + 23068672);    // 2MB
  float* alphaf = (float*)(ws + 25165824); // 16KB
  float* biasf  = (float*)(ws + 25182208); // 16KB
  u16*   vtbuf = (u16*)(ws + 25198592);    // 16MB
  u16*   ybuf  = xb;
  u16*   qbuf  = (u16*)d_out;              // d_out (32MB) as Q|K scratch
  u16*   kbuf  = (u16*)d_out + 8388608;
  float* outf  = (float*)d_out;

  k_prep<<<5120, 256, 0, stream>>>(x, xb, Wq, Wk, Wv, Wp, bq, bk, bv, bp, wbqkv, wbp, alphaf, biasf);
  k_gemm<0, 24, 1536><<<1536, 256, 0, stream>>>(xb, wbqkv, alphaf, biasf, qbuf, kbuf, vtbuf, nullptr);
  k_attn<<<1024, 512, 0, stream>>>(qbuf, kbuf, vtbuf, ybuf);
  k_gemm<1, 8, 512><<<512, 256, 0, stream>>>(ybuf, wbp, alphaf, biasf, nullptr, nullptr, nullptr, outf);
}

// Round 14
// 154.145 us; speedup vs baseline: 1.0700x; 1.0700x over previous
//
#include <hip/hip_runtime.h>
#include <hip/hip_bf16.h>

typedef short s16x8 __attribute__((ext_vector_type(8)));
typedef float f32x4 __attribute__((ext_vector_type(4)));
typedef unsigned u32x4 __attribute__((ext_vector_type(4)));
typedef unsigned short u16;

#define LOG2E 1.4426950408889634f
#define QSC (0.125f * LOG2E)   // softmax scale (Dh=64 -> 1/8) * log2(e), folded into alpha_q/bias_q

typedef __attribute__((address_space(3))) unsigned int lds_u32;
typedef __attribute__((address_space(1))) const unsigned int glb_u32;

static __device__ __forceinline__ void gload16(const void* g, void* l) {
  __builtin_amdgcn_global_load_lds((glb_u32*)g, (lds_u32*)l, 16, 0, 0);
}
static __device__ __forceinline__ u16 bf16u(float f) {
  unsigned u = __builtin_bit_cast(unsigned, f);
  return (u16)((u + 0x7FFFu + ((u >> 16) & 1u)) >> 16);  // RNE
}
static __device__ __forceinline__ unsigned pk(u16 a, u16 b) {
  return (unsigned)a | ((unsigned)b << 16);
}
// packed RNE f32x2 -> bf16x2, single HW op (no builtin on gfx950 - T12 recipe)
static __device__ __forceinline__ unsigned cvtpk(float lo, float hi) {
  unsigned d;
  asm("v_cvt_pk_bf16_f32 %0, %1, %2" : "=v"(d) : "v"(lo), "v"(hi));
  return d;
}
// header path (used only in non-hot prep)
static __device__ __forceinline__ unsigned pk2(float a, float b) {
  float2 f; f.x = a; f.y = b;
  __hip_bfloat162 h = __float22bfloat162_rn(f);
  unsigned r;
  __builtin_memcpy(&r, &h, 4);
  return r;
}

// ---------------------------------------------------------------------------
// Prep (merged): blocks 0..1023 binarize weights; blocks 1024..5119 cvt x.
// ---------------------------------------------------------------------------
__global__ __launch_bounds__(256) void k_prep(
    const float* __restrict__ x, u16* __restrict__ xb,
    const float* __restrict__ Wq, const float* __restrict__ Wk,
    const float* __restrict__ Wv, const float* __restrict__ Wp,
    const float* __restrict__ bq, const float* __restrict__ bk,
    const float* __restrict__ bv, const float* __restrict__ bp,
    u16* __restrict__ wbqkv, u16* __restrict__ wbp,
    float* __restrict__ alphaf, float* __restrict__ biasf) {
  if (blockIdx.x >= 1024) {
    int i = ((blockIdx.x - 1024) * 256 + threadIdx.x) * 8;
    float4 a = *reinterpret_cast<const float4*>(x + i);
    float4 b = *reinterpret_cast<const float4*>(x + i + 4);
    uint4 w = { pk2(a.x, a.y), pk2(a.z, a.w), pk2(b.x, b.y), pk2(b.z, b.w) };
    *reinterpret_cast<uint4*>(xb + i) = w;
    return;
  }
  int wave = threadIdx.x >> 6, lane = threadIdx.x & 63;
  int row = blockIdx.x * 4 + wave;
  const float* src; const float* bias; int r;
  if (row < 1024)      { src = Wq; bias = bq; r = row; }
  else if (row < 2048) { src = Wk; bias = bk; r = row - 1024; }
  else if (row < 3072) { src = Wv; bias = bv; r = row - 2048; }
  else                 { src = Wp; bias = bp; r = row - 3072; }
  const float4* s4 = reinterpret_cast<const float4*>(src + r * 1024);
  float4 v[4];
  float asum = 0.f;
#pragma unroll
  for (int i = 0; i < 4; ++i) {
    v[i] = s4[lane * 4 + i];
    asum += fabsf(v[i].x) + fabsf(v[i].y) + fabsf(v[i].z) + fabsf(v[i].w);
  }
#pragma unroll
  for (int m = 32; m >= 1; m >>= 1) asum += __shfl_xor(asum, m, 64);
  float alpha = asum * (1.0f / 1024.0f);

  u16 o[16];
#pragma unroll
  for (int i = 0; i < 4; ++i) {
    const float* f = reinterpret_cast<const float*>(&v[i]);
#pragma unroll
    for (int j = 0; j < 4; ++j) {
      float w = f[j];
      o[i * 4 + j] = (w > 0.f) ? (u16)0x3F80 : ((w < 0.f) ? (u16)0xBF80 : (u16)0);
    }
  }
  u16* dst = (row < 3072 ? wbqkv + row * 1024 : wbp + (row - 3072) * 1024) + lane * 16;
  uint4 w0 = { pk(o[0],o[1]), pk(o[2],o[3]), pk(o[4],o[5]), pk(o[6],o[7]) };
  uint4 w1 = { pk(o[8],o[9]), pk(o[10],o[11]), pk(o[12],o[13]), pk(o[14],o[15]) };
  reinterpret_cast<uint4*>(dst)[0] = w0;
  reinterpret_cast<uint4*>(dst)[1] = w1;
  if (lane == 0) {
    float sc = (row < 1024) ? QSC : 1.0f;
    alphaf[row] = alpha * sc;
    biasf[row]  = bias[r] * sc;
  }
}

// ---------------------------------------------------------------------------
// GEMM v2 (unchanged from R11, passing): 128x128 tile, BK=64, 4 waves,
// 16x16x32 MFMA, XCD-swizzled grid, double-buffered staging.
// ---------------------------------------------------------------------------
template <int MODE, int NX, int NWG>
__global__ __launch_bounds__(256) void k_gemm(
    const u16* __restrict__ A, const u16* __restrict__ Bw,
    const float* __restrict__ alphaf, const float* __restrict__ biasf,
    u16* __restrict__ qbuf, u16* __restrict__ kbuf, u16* __restrict__ vtbuf,
    float* __restrict__ outf) {
  __shared__ alignas(128) char smem[65536];  // 2 x (A 16K | B 16K)
  int tid = threadIdx.x;
  int wave = tid >> 6, l = tid & 63, g = l >> 4, ln = l & 15;
  int wm = (wave >> 1) * 64, wn = (wave & 1) * 64;
  int wg = (blockIdx.x & 7) * (NWG / 8) + (blockIdx.x >> 3);  // XCD swizzle
  int m0 = (wg / NX) * 128, n0 = (wg % NX) * 128;

  f32x4 acc[4][4];
#pragma unroll
  for (int i = 0; i < 4; ++i)
#pragma unroll
    for (int j = 0; j < 4; ++j) acc[i][j] = f32x4{0.f, 0.f, 0.f, 0.f};

  const char* Ab = reinterpret_cast<const char*>(A) + m0 * 2048;
  const char* Bb = reinterpret_cast<const char*>(Bw) + n0 * 2048;

  int soff[4];
#pragma unroll
  for (int i = 0; i < 4; ++i) {
    int P = i * 4096 + tid * 16;
    int r = P >> 7;
    int kc = ((P >> 4) & 7) ^ (r & 7);
    soff[i] = r * 2048 + kc * 16;
  }

  // prologue: stage K-step 0 into buf0
#pragma unroll
  for (int i = 0; i < 4; ++i)
    gload16(Ab + soff[i], smem + i * 4096 + wave * 1024);
#pragma unroll
  for (int i = 0; i < 4; ++i)
    gload16(Bb + soff[i], smem + 16384 + i * 4096 + wave * 1024);
  __syncthreads();

  for (int ks = 0; ks < 16; ++ks) {
    int cb = ks & 1;
    if (ks < 15) {  // prefetch next K-step into the other buffer
      char* nb = smem + (cb ^ 1) * 32768;
      int kb0 = (ks + 1) * 128;
#pragma unroll
      for (int i = 0; i < 4; ++i)
        gload16(Ab + soff[i] + kb0, nb + i * 4096 + wave * 1024);
#pragma unroll
      for (int i = 0; i < 4; ++i)
        gload16(Bb + soff[i] + kb0, nb + 16384 + i * 4096 + wave * 1024);
    }
    const char* As = smem + cb * 32768;
    const char* Bs = As + 16384;
#pragma unroll
    for (int kk = 0; kk < 2; ++kk) {
      s16x8 af[4], bfr[4];
#pragma unroll
      for (int mf = 0; mf < 4; ++mf) {
        int r = wm + mf * 16 + ln;
        int kb = (kk * 64 + g * 16) ^ ((r & 7) << 4);
        af[mf] = *reinterpret_cast<const s16x8*>(As + r * 128 + kb);
      }
#pragma unroll
      for (int nf = 0; nf < 4; ++nf) {
        int r = wn + nf * 16 + ln;
        int kb = (kk * 64 + g * 16) ^ ((r & 7) << 4);
        bfr[nf] = *reinterpret_cast<const s16x8*>(Bs + r * 128 + kb);
      }
#pragma unroll
      for (int mf = 0; mf < 4; ++mf)
#pragma unroll
        for (int nf = 0; nf < 4; ++nf)
          acc[mf][nf] = __builtin_amdgcn_mfma_f32_16x16x32_bf16(af[mf], bfr[nf], acc[mf][nf], 0, 0, 0);
    }
    __syncthreads();  // drains prefetch vmcnt; buf swap safe
  }

  if (MODE == 0) {
    if (n0 < 2048) {
      u16* dst = (n0 < 1024) ? qbuf : kbuf;
#pragma unroll
      for (int nf = 0; nf < 4; ++nf) {
        int n = n0 + wn + nf * 16 + ln;
        float al = alphaf[n], bi = biasf[n];
        int nl = n & 1023;
        int h = nl >> 6, d = nl & 63;
#pragma unroll
        for (int mf = 0; mf < 4; ++mf)
#pragma unroll
          for (int rg = 0; rg < 4; ++rg) {
            int m = m0 + wm + mf * 16 + g * 4 + rg;
            int b = m >> 11, t = m & 2047;
            dst[(((b * 16 + h) * 2048 + t) << 6) + d] = bf16u(al * acc[mf][nf][rg] + bi);
          }
      }
    } else {
      u16* ldsT = reinterpret_cast<u16*>(smem);
#pragma unroll
      for (int nf = 0; nf < 4; ++nf) {
        int n = n0 + wn + nf * 16 + ln;
        float al = alphaf[n], bi = biasf[n];
        int nloc = wn + nf * 16 + ln;
#pragma unroll
        for (int mf = 0; mf < 4; ++mf)
#pragma unroll
          for (int rg = 0; rg < 4; ++rg) {
            int mloc = wm + mf * 16 + g * 4 + rg;
            ldsT[mloc * 132 + nloc] = bf16u(al * acc[mf][nf][rg] + bi);
          }
      }
      __syncthreads();
      int dl = tid >> 1;
      int sh = (tid & 1) * 64;
      int nv = n0 - 2048 + dl;
      int h = nv >> 6, d = nv & 63;
      int b = m0 >> 11;
      int s0 = (m0 & 2047) + sh;
      u16* vdst = vtbuf + (((b * 16 + h) * 64 + d) << 11) + s0;
#pragma unroll
      for (int c8 = 0; c8 < 8; ++c8) {
        u16 t0 = ldsT[(sh + c8 * 8 + 0) * 132 + dl], t1 = ldsT[(sh + c8 * 8 + 1) * 132 + dl];
        u16 t2 = ldsT[(sh + c8 * 8 + 2) * 132 + dl], t3 = ldsT[(sh + c8 * 8 + 3) * 132 + dl];
        u16 t4 = ldsT[(sh + c8 * 8 + 4) * 132 + dl], t5 = ldsT[(sh + c8 * 8 + 5) * 132 + dl];
        u16 t6 = ldsT[(sh + c8 * 8 + 6) * 132 + dl], t7 = ldsT[(sh + c8 * 8 + 7) * 132 + dl];
        uint4 w = { pk(t0, t1), pk(t2, t3), pk(t4, t5), pk(t6, t7) };
        *reinterpret_cast<uint4*>(vdst + c8 * 8) = w;
      }
    }
  } else {
#pragma unroll
    for (int nf = 0; nf < 4; ++nf) {
      int n = n0 + wn + nf * 16 + ln;
      float al = alphaf[3072 + n], bi = biasf[3072 + n];
#pragma unroll
      for (int mf = 0; mf < 4; ++mf)
#pragma unroll
        for (int rg = 0; rg < 4; ++rg) {
          int m = m0 + wm + mf * 16 + g * 4 + rg;
          outf[m * 1024 + n] = al * acc[mf][nf][rg] + bi;
        }
    }
  }
}

// ---------------------------------------------------------------------------
// Flash attention v8: R11 structure (8 waves x 32 q-rows, grid 512, lane-
// local P, fixed m=0, ones-MFMA l, zero-conflict swizzles) with KVBLK=128:
// 16 steps (half the barrier drains), each step = 4 independent sub-phases
// (QK 8-MFMA -> exp2/pack -> l + PV 8-MFMA) so adjacent sub-phases' MFMA and
// VALU work can overlap (R11: MfmaUtil 47 + VALUBusy 44 = serialized pipes).
// K-row permutation rho(t,m) = 32(t&3) + 8(m>>2) + 4(t>>2) + (m&3):
// lane (g,ln) reg rg of MFMA t = S[q][s = 32(t&3) + 8g + 4(t>>2) + rg],
// so pf[c] packs p[t=c] (j=0..3) and p[t=c+4] (j=4..7), all lane-local.
// Summation order identical to v6 -> bit-identical output.
// ---------------------------------------------------------------------------
__global__ __launch_bounds__(512, 4) void k_attn(
    const u16* __restrict__ qb, const u16* __restrict__ kb,
    const u16* __restrict__ vtb, u16* __restrict__ yb) {
  __shared__ alignas(128) char smem[65536];  // K dbuf 2x16K | V dbuf 2x16K
  int tid = threadIdx.x;
  int wave = tid >> 6, lane = tid & 63;
  int g = lane >> 4, ln = lane & 15;

  // XCD swizzle: 8 q-tiles of one bh on one XCD (K/V of 8 heads = 4MB = L2)
  int wg = (blockIdx.x & 7) * 64 + (blockIdx.x >> 3);
  int bh = wg >> 3, qt = wg & 7;
  const char* Qg = reinterpret_cast<const char*>(qb) + bh * 262144;
  const char* Kg = reinterpret_cast<const char*>(kb) + bh * 262144;
  const char* Vg = reinterpret_cast<const char*>(vtb) + bh * 262144;  // [64 d][2048 s]

  // Q fragments: lane (g,ln) holds Q[qrow][k = 32kt + 8g + j]; 2 q-sets
  int qrow = qt * 256 + wave * 32 + ln;
  const s16x8* Qr0 = reinterpret_cast<const s16x8*>(Qg + qrow * 128);
  const s16x8* Qr1 = reinterpret_cast<const s16x8*>(Qg + (qrow + 16) * 128);
  s16x8 qf[2][2];
  qf[0][0] = Qr0[g]; qf[0][1] = Qr0[g + 4];
  qf[1][0] = Qr1[g]; qf[1][1] = Qr1[g + 4];

  s16x8 ones;
#pragma unroll
  for (int i = 0; i < 8; ++i) ones[i] = (short)0x3F80;

  // staging offsets, w(r) = (r&3)|(bit3(r)<<2), inverse-swizzled source.
  // K tile: 128 rows x 128B (16KB, 2 rounds). V tile: 64 rows x 256B (16KB).
  int ksrc[2], vsrc[2];
#pragma unroll
  for (int i = 0; i < 2; ++i) {
    int P = i * 8192 + tid * 16;
    int rk = P >> 7, kck = (P >> 4) & 7;
    int wk = (rk & 3) | (((rk >> 3) & 1) << 2);
    ksrc[i] = rk * 128 + (kck ^ wk) * 16;
    int rv = P >> 8, kcv = (P >> 4) & 15;
    int wv = (rv & 3) | (((rv >> 3) & 1) << 2);
    vsrc[i] = rv * 4096 + (kcv ^ wv) * 16;
  }

  // read-side XOR bytes
  int swK = (ln & 7) << 4;                              // w(rho) = ln&7
  int swV = ((ln & 3) | (((ln >> 3) & 1) << 2)) << 4;   // w(dt*16+ln)

  f32x4 oacc[2][4];
#pragma unroll
  for (int s = 0; s < 2; ++s)
#pragma unroll
    for (int i = 0; i < 4; ++i) oacc[s][i] = f32x4{0.f, 0.f, 0.f, 0.f};
  f32x4 lacc[2];
  lacc[0] = f32x4{0.f, 0.f, 0.f, 0.f};
  lacc[1] = f32x4{0.f, 0.f, 0.f, 0.f};

  // prologue: stage tile 0 into buf0
#pragma unroll
  for (int i = 0; i < 2; ++i) {
    gload16(Kg + ksrc[i], smem + i * 8192 + wave * 1024);
    gload16(Vg + vsrc[i], smem + 32768 + i * 8192 + wave * 1024);
  }
  __syncthreads();

  for (int st = 0; st < 16; ++st) {
    int cb = st & 1;
    if (st < 15) {  // prefetch next tile into the other buffer
      char* nk = smem + (cb ^ 1) * 16384;
      char* nv = smem + 32768 + (cb ^ 1) * 16384;
      const char* gk = Kg + (st + 1) * 16384;
      const char* gv = Vg + (st + 1) * 256;
#pragma unroll
      for (int i = 0; i < 2; ++i) {
        gload16(gk + ksrc[i], nk + i * 8192 + wave * 1024);
        gload16(gv + vsrc[i], nv + i * 8192 + wave * 1024);
      }
    }
    const char* Kb = smem + cb * 16384;
    const char* Vb = smem + 32768 + cb * 16384;

    // 4 sub-phases: c = kt' (s-slice of 32)
#pragma unroll
    for (int c = 0; c < 4; ++c) {
      // QK^T: t = c and t = c+4; rho = 32c + 8(ln>>2) + 4(t>>2) + (ln&3)
      f32x4 sa[2][2];
#pragma unroll
      for (int s = 0; s < 2; ++s)
#pragma unroll
        for (int h = 0; h < 2; ++h) sa[s][h] = f32x4{0.f, 0.f, 0.f, 0.f};
      int rho0 = 32 * c + 8 * (ln >> 2) + (ln & 3);
      __builtin_amdgcn_s_setprio(1);
#pragma unroll
      for (int kt = 0; kt < 2; ++kt) {
        int off = (kt * 64 + g * 16) ^ swK;
        s16x8 kf0 = *reinterpret_cast<const s16x8*>(Kb + rho0 * 128 + off);
        s16x8 kf1 = *reinterpret_cast<const s16x8*>(Kb + (rho0 + 4) * 128 + off);
        sa[0][0] = __builtin_amdgcn_mfma_f32_16x16x32_bf16(kf0, qf[0][kt], sa[0][0], 0, 0, 0);
        sa[1][0] = __builtin_amdgcn_mfma_f32_16x16x32_bf16(kf0, qf[1][kt], sa[1][0], 0, 0, 0);
        sa[0][1] = __builtin_amdgcn_mfma_f32_16x16x32_bf16(kf1, qf[0][kt], sa[0][1], 0, 0, 0);
        sa[1][1] = __builtin_amdgcn_mfma_f32_16x16x32_bf16(kf1, qf[1][kt], sa[1][1], 0, 0, 0);
      }
      __builtin_amdgcn_s_setprio(0);

      // P = exp2(S), pack lane-locally: pf positions j=0..3 from t=c (h=0),
      // j=4..7 from t=c+4 (h=1)
      s16x8 pf[2];
#pragma unroll
      for (int s = 0; s < 2; ++s) {
        float p0 = __builtin_amdgcn_exp2f(sa[s][0][0]);
        float p1 = __builtin_amdgcn_exp2f(sa[s][0][1]);
        float p2 = __builtin_amdgcn_exp2f(sa[s][0][2]);
        float p3 = __builtin_amdgcn_exp2f(sa[s][0][3]);
        float p4 = __builtin_amdgcn_exp2f(sa[s][1][0]);
        float p5 = __builtin_amdgcn_exp2f(sa[s][1][1]);
        float p6 = __builtin_amdgcn_exp2f(sa[s][1][2]);
        float p7 = __builtin_amdgcn_exp2f(sa[s][1][3]);
        u32x4 tw;
        tw[0] = cvtpk(p0, p1);
        tw[1] = cvtpk(p2, p3);
        tw[2] = cvtpk(p4, p5);
        tw[3] = cvtpk(p6, p7);
        pf[s] = __builtin_bit_cast(s16x8, tw);
      }

      // l += ones . P
      lacc[0] = __builtin_amdgcn_mfma_f32_16x16x32_bf16(ones, pf[0], lacc[0], 0, 0, 0);
      lacc[1] = __builtin_amdgcn_mfma_f32_16x16x32_bf16(ones, pf[1], lacc[1], 0, 0, 0);

      // O^T += mfma(V, P): s-slice c; V row = dt*16+ln, col byte = c*64+g*16
      int offv = (c * 64 + g * 16) ^ swV;
      __builtin_amdgcn_s_setprio(1);
#pragma unroll
      for (int dt = 0; dt < 4; ++dt) {
        s16x8 vf = *reinterpret_cast<const s16x8*>(Vb + (dt * 16 + ln) * 256 + offv);
        oacc[0][dt] = __builtin_amdgcn_mfma_f32_16x16x32_bf16(vf, pf[0], oacc[0][dt], 0, 0, 0);
        oacc[1][dt] = __builtin_amdgcn_mfma_f32_16x16x32_bf16(vf, pf[1], oacc[1][dt], 0, 0, 0);
      }
      __builtin_amdgcn_s_setprio(0);
    }
    __syncthreads();  // drains vmcnt (prefetch) + lgkm; buf swap safe
  }

  // epilogue: y[b, t, h*64 + d] = O[d][q]/l, d = 16dt + 4g + rg
  int b = bh >> 4, h = bh & 15;
#pragma unroll
  for (int s = 0; s < 2; ++s) {
    float linv = 1.0f / lacc[s][0];
    u16* yrow = yb + (b * 2048 + qrow + s * 16) * 1024 + h * 64;
#pragma unroll
    for (int dt = 0; dt < 4; ++dt) {
      uint2 w;
      w.x = cvtpk(oacc[s][dt][0] * linv, oacc[s][dt][1] * linv);
      w.y = cvtpk(oacc[s][dt][2] * linv, oacc[s][dt][3] * linv);
      *reinterpret_cast<uint2*>(yrow + dt * 16 + g * 4) = w;
    }
  }
}

// ---------------------------------------------------------------------------
extern "C" void kernel_launch(void* const* d_in, const int* in_sizes, int n_in,
                              void* d_out, int out_size, void* d_ws, size_t ws_size,
                              hipStream_t stream) {
  (void)in_sizes; (void)n_in; (void)out_size; (void)ws_size;
  const float* x  = (const float*)d_in[0];
  const float* Wq = (const float*)d_in[1];
  const float* bq = (const float*)d_in[2];
  const float* Wk = (const float*)d_in[3];
  const float* bk = (const float*)d_in[4];
  const float* Wv = (const float*)d_in[5];
  const float* bv = (const float*)d_in[6];
  const float* Wp = (const float*)d_in[7];
  const float* bp = (const float*)d_in[8];

  char* ws = (char*)d_ws;
  u16*   xb    = (u16*)(ws);               // 16MB (reused as Y after attention)
  u16*   wbqkv = (u16*)(ws + 16777216);    // 6MB
  u16*   wbp   = (u16*)(ws + 23068672);    // 2MB
  float* alphaf = (float*)(ws + 25165824); // 16KB
  float* biasf  = (float*)(ws + 25182208); // 16KB
  u16*   vtbuf = (u16*)(ws + 25198592);    // 16MB
  u16*   ybuf  = xb;
  u16*   qbuf  = (u16*)d_out;              // d_out (32MB) as Q|K scratch
  u16*   kbuf  = (u16*)d_out + 8388608;
  float* outf  = (float*)d_out;

  k_prep<<<5120, 256, 0, stream>>>(x, xb, Wq, Wk, Wv, Wp, bq, bk, bv, bp, wbqkv, wbp, alphaf, biasf);
  k_gemm<0, 24, 1536><<<1536, 256, 0, stream>>>(xb, wbqkv, alphaf, biasf, qbuf, kbuf, vtbuf, nullptr);
  k_attn<<<512, 512, 0, stream>>>(qbuf, kbuf, vtbuf, ybuf);
  k_gemm<1, 8, 512><<<512, 256, 0, stream>>>(ybuf, wbp, alphaf, biasf, nullptr, nullptr, nullptr, outf);
}